// Round 1
// 202.504 us; speedup vs baseline: 1.0191x; 1.0191x over previous
//
#include <hip/hip_runtime.h>
#include <math.h>

namespace {

typedef __bf16 bf16x8 __attribute__((ext_vector_type(8)));
typedef float  f32x4  __attribute__((ext_vector_type(4)));
typedef float  f32x2  __attribute__((ext_vector_type(2)));

constexpr int B_      = 65536;
constexpr int OBS_DIM_= 85;
constexpr int NL_     = 5;
constexpr int NT_     = 10;
constexpr int HID_    = 64;
constexpr int NACT_   = 5;
constexpr float ALPHA_= 0.01f;

// 2-inst leaky: x>0 -> min(x,0)=0 -> x ; x<0 -> x + (a-1)x = a*x
__device__ __forceinline__ float leaky(float x)    { return fmaf(fminf(x, 0.0f), ALPHA_ - 1.0f, x); }
__device__ __forceinline__ float sigmoidf(float x) { return 1.0f / (1.0f + __expf(-x)); }
__device__ __forceinline__ float tanh_fast(float x){ return 1.0f - 2.0f / (__expf(2.0f * x) + 1.0f); }

// ---------------------------------------------------------------------------
// Prep: Wa = W@a  ((h_mix@W)@a == h_mix@(W@a): kills the 64x64 matmul), plus
// bf16 weights for the MFMA kernel. ws: [0,512) Wa f32; Wih; Whh; Wf1T(64x96).
// GRU weights are stored COLUMN-PERMUTED: within each 64-row gate block,
// permuted row q = nt*16+l holds original row 4*l+nt. This makes the gemm
// epilogue own contiguous original columns 4l..4l+3 per lane -> f32x4 loads
// of biases/hidden/w_fc2 and coalesced f32x4 h_out stores.
// ---------------------------------------------------------------------------
__global__ void prep_kernel(const float* __restrict__ W, const float* __restrict__ a,
                            const float* __restrict__ w_ih, const float* __restrict__ w_hh,
                            const float* __restrict__ w_fc1, void* __restrict__ ws) {
  float* Wa   = (float*)ws;
  __bf16* ih  = (__bf16*)((char*)ws + 512);
  __bf16* hh  = ih + 192 * 64;
  __bf16* f1t = hh + 192 * 64;
  const int tid = blockIdx.x * 256 + threadIdx.x;
  if (blockIdx.x == 0 && threadIdx.x < 64) {
    const int i = threadIdx.x;
    float s1 = 0.0f, s2 = 0.0f;
    #pragma unroll
    for (int j = 0; j < 64; ++j) {
      float w = W[i * 64 + j];
      s1 += w * a[j];
      s2 += w * a[64 + j];
    }
    Wa[i] = s1;
    Wa[64 + i] = s2;
  }
  const int stride = gridDim.x * 256;
  for (int i = tid; i < 192 * 64; i += stride) {
    int pr = i >> 6, k = i & 63;
    int g  = pr >> 6;          // gate block 0/1/2
    int q  = pr & 63;
    int orig = (g << 6) + ((q & 15) << 2) + (q >> 4);   // 4*l + nt
    ih[i] = (__bf16)w_ih[orig * 64 + k];
    hh[i] = (__bf16)w_hh[orig * 64 + k];
  }
  for (int i = tid; i < 64 * 96; i += stride) {
    int n = i / 96, k = i - 96 * n;
    f1t[i] = (__bf16)(k < 90 ? w_fc1[k * 64 + n] : 0.0f);
  }
}

// ======================= FRONT KERNEL (unchanged) =======================
__global__ __launch_bounds__(256) void front_kernel(
    const float* __restrict__ obs,
    const float* __restrict__ w_in0, const float* __restrict__ b_in0,
    const float* __restrict__ w_in1, const float* __restrict__ b_in1,
    const float* __restrict__ w_in2, const float* __restrict__ b_in2,
    const float* __restrict__ w_o1, const float* __restrict__ b_o1,
    const float* __restrict__ w_o2, const float* __restrict__ b_o2,
    const float* __restrict__ w_o3, const float* __restrict__ b_o3,
    const float* __restrict__ Wa,
    float* __restrict__ out5) {

  __shared__ __align__(16) float s_obs[16][84];
  __shared__ float s_wh1[16][12], s_wh2[16][12];
  __shared__ float s_colm[16][6], s_cols[16][6];
  __shared__ __align__(16) float s_att[16][5][12];  // stride 12: f32x2-aligned
  __shared__ __align__(16) float s_h1[16][5][36];   // stride 36: f32x4-aligned rows
  __shared__ __align__(16) float s_h2[16][5][20];   // stride 20: f32x4-aligned rows
  __shared__ float s_hp[16][6];

  const int tid  = threadIdx.x;
  const int wv   = tid >> 6;
  const int lane = tid & 63;
  const int l16  = lane & 15;
  const int rloc = tid >> 4;                // 0..15 (four rows per wave)
  const long gr0 = (long)blockIdx.x * 16;

  // wave-local staging: this wave's 4 rows, cols 0..79 (320 = 5*64 exactly)
  {
    const float* src = obs + (gr0 + wv * 4) * OBS_DIM_;
    #pragma unroll
    for (int c0 = 0; c0 < 5; ++c0) {
      int it = c0 * 64 + lane;
      int r = it / 80, c = it - 80 * r;
      s_obs[wv * 4 + r][c] = src[r * OBS_DIM_ + c];
    }
  }

  const int u0 = l16 * 4;                   // my 4 INF units
  const float* orow = s_obs[rloc];
  const f32x4 wa1 = *(const f32x4*)&Wa[u0];
  const f32x4 wa2 = *(const f32x4*)&Wa[64 + u0];

  // stage-1: class weights in 8 f32x4 regs, uniform reload at t=5 / t=9
  f32x4 wA[8];
  #pragma unroll
  for (int f = 0; f < 8; ++f) wA[f] = *(const f32x4*)&w_in0[f * 64 + u0];
  f32x4 bA = *(const f32x4*)&b_in0[u0];

  #pragma unroll
  for (int t = 0; t < NT_; ++t) {
    if (t == 5) {
      #pragma unroll
      for (int f = 0; f < 8; ++f) wA[f] = *(const f32x4*)&w_in1[f * 64 + u0];
      bA = *(const f32x4*)&b_in1[u0];
    }
    if (t == 9) {
      #pragma unroll
      for (int f = 0; f < 8; ++f) wA[f] = *(const f32x4*)&w_in2[f * 64 + u0];
      bA = *(const f32x4*)&b_in2[u0];
    }
    const int ia = t * 8 + 4;               // feats 0..3 (never wraps)
    int ib = t * 8 + 8;                     // feats 4..7 (wraps only at t=9)
    if (ib >= 80) ib = 0;
    f32x4 oa = *(const f32x4*)&orow[ia];
    f32x4 ob = *(const f32x4*)&orow[ib];
    f32x4 z = bA;
    #pragma unroll
    for (int f = 0; f < 4; ++f) {
      z[0] += oa[f] * wA[f][0]; z[1] += oa[f] * wA[f][1];
      z[2] += oa[f] * wA[f][2]; z[3] += oa[f] * wA[f][3];
    }
    #pragma unroll
    for (int f = 4; f < 8; ++f) {
      z[0] += ob[f - 4] * wA[f][0]; z[1] += ob[f - 4] * wA[f][1];
      z[2] += ob[f - 4] * wA[f][2]; z[3] += ob[f - 4] * wA[f][3];
    }
    float h0 = leaky(z[0]), h1 = leaky(z[1]), h2 = leaky(z[2]), h3 = leaky(z[3]);
    float p1t = h0 * wa1[0] + h1 * wa1[1] + h2 * wa1[2] + h3 * wa1[3];
    float p2t = h0 * wa2[0] + h1 * wa2[1] + h2 * wa2[2] + h3 * wa2[3];
    // butterfly within the 16-lane row group
    p1t += __shfl_xor(p1t, 1, 64);  p2t += __shfl_xor(p2t, 1, 64);
    p1t += __shfl_xor(p1t, 2, 64);  p2t += __shfl_xor(p2t, 2, 64);
    p1t += __shfl_xor(p1t, 4, 64);  p2t += __shfl_xor(p2t, 4, 64);
    p1t += __shfl_xor(p1t, 8, 64);  p2t += __shfl_xor(p2t, 8, 64);
    if (l16 == 0) { s_wh1[rloc][t] = p1t; s_wh2[rloc][t] = p2t; }
  }

  // lanes 5..9 of each group: att1 column softmax stats (column jj = l16-5)
  if (l16 >= 5 && l16 < 10) {
    const int jj = l16 - 5;
    float w1v = s_wh1[rloc][NL_ + jj];
    float ev[NL_], m = -1e30f;
    #pragma unroll
    for (int k = 0; k < NL_; ++k) { ev[k] = leaky(w1v + s_wh2[rloc][k]); m = fmaxf(m, ev[k]); }
    float s = 0.0f;
    #pragma unroll
    for (int k = 0; k < NL_; ++k) s += __expf(ev[k] - m);
    s_colm[rloc][jj] = m;
    s_cols[rloc][jj] = s;
  }

  // lanes 0..4: attention row r = l16 -> s_att
  if (l16 < NL_) {
    const int r = l16;
    const float wh1_r = s_wh1[rloc][r];
    const float wh2_r = s_wh2[rloc][r];
    float ev[NL_], m = -1e30f;
    #pragma unroll
    for (int j = 0; j < NL_; ++j) { ev[j] = leaky(wh1_r + s_wh2[rloc][NL_ + j]); m = fmaxf(m, ev[j]); }
    float a0[NL_], s = 0.0f;
    #pragma unroll
    for (int j = 0; j < NL_; ++j) { a0[j] = __expf(ev[j] - m); s += a0[j]; }
    float inv = 1.0f / s;
    #pragma unroll
    for (int j = 0; j < NL_; ++j) s_att[rloc][r][j] = a0[j] * inv;
    #pragma unroll
    for (int jj = 0; jj < NL_; ++jj) {
      float e = leaky(s_wh1[rloc][NL_ + jj] + wh2_r);
      s_att[rloc][r][NL_ + jj] = __expf(e - s_colm[rloc][jj]) / s_cols[rloc][jj];
    }
  }

  // h1: lane owns units 2*l16, 2*l16+1; w_o1 cols as 10 f32x2 regs, att rows
  // read as 5 f32x2 (stride-12 rows keep 8B alignment).
  {
    f32x2 w1c[NT_];
    #pragma unroll
    for (int k = 0; k < NT_; ++k) w1c[k] = *(const f32x2*)&w_o1[k * 32 + l16 * 2];
    const f32x2 b1 = *(const f32x2*)&b_o1[l16 * 2];
    #pragma unroll
    for (int r5 = 0; r5 < NL_; ++r5) {
      float za = b1[0], zb = b1[1];
      #pragma unroll
      for (int k2 = 0; k2 < 5; ++k2) {
        f32x2 at = *(const f32x2*)&s_att[rloc][r5][k2 * 2];
        za += at[0] * w1c[2 * k2][0] + at[1] * w1c[2 * k2 + 1][0];
        zb += at[0] * w1c[2 * k2][1] + at[1] * w1c[2 * k2 + 1][1];
      }
      *(f32x2*)&s_h1[rloc][r5][l16 * 2] = f32x2{leaky(za), leaky(zb)};
    }
  }

  // h2: lane owns unit c = l16 (exactly 16 units); w_o2 column in 32 regs,
  // h1 rows read as f32x4 (stride-36 rows keep 16B alignment).
  {
    float w2c[32];
    #pragma unroll
    for (int k = 0; k < 32; ++k) w2c[k] = w_o2[k * 16 + l16];
    const float b2 = b_o2[l16];
    #pragma unroll
    for (int r5 = 0; r5 < NL_; ++r5) {
      float z = b2;
      #pragma unroll
      for (int k4 = 0; k4 < 8; ++k4) {
        f32x4 hv = *(const f32x4*)&s_h1[rloc][r5][k4 * 4];
        z += hv[0] * w2c[4 * k4] + hv[1] * w2c[4 * k4 + 1]
           + hv[2] * w2c[4 * k4 + 2] + hv[3] * w2c[4 * k4 + 3];
      }
      s_h2[rloc][r5][l16] = leaky(z);
    }
  }

  // hp + softmax + store (lanes 0..4 of each group)
  if (l16 < NL_) {
    float z3 = b_o3[0];
    #pragma unroll
    for (int k4 = 0; k4 < 4; ++k4) {
      f32x4 hv = *(const f32x4*)&s_h2[rloc][l16][k4 * 4];
      z3 += hv[0] * w_o3[4 * k4] + hv[1] * w_o3[4 * k4 + 1]
          + hv[2] * w_o3[4 * k4 + 2] + hv[3] * w_o3[4 * k4 + 3];
    }
    float hp_own = leaky(z3);
    s_hp[rloc][l16] = hp_own;
    float m5 = -1e30f;
    #pragma unroll
    for (int j = 0; j < NL_; ++j) m5 = fmaxf(m5, s_hp[rloc][j]);
    float ssum = 0.0f;
    #pragma unroll
    for (int j = 0; j < NL_; ++j) ssum += __expf(s_hp[rloc][j] - m5);
    out5[(gr0 + rloc) * NL_ + l16] = __expf(hp_own - m5) / ssum;
  }
}

// ======================= GEMM KERNEL =======================
// r12: latency attack. (a) __launch_bounds__(256,4): VGPR cap 64->128 (the
// grid caps occupancy at 16 waves/CU anyway -- 4 blocks/CU is all we can get,
// so spend the registers). (b) issue-early: ALL global loads (obs staging,
// o5, hidden A-frags, 12 fc1 B-frags) issued before any convert/LDS work ->
// one combined latency instead of serial load->drain->use phases. (c) GRU
// output columns permuted (see prep): lane owns orig cols 4l..4l+3 -> f32x4
// bias/hidden/w_fc2 loads and COALESCED f32x4 h_out stores (write-amp fix).
constexpr int ROWS_ = 64;     // 4 waves x 16-row tiles
constexpr int SOB_  = 104;    // bf16 stride: 208B -> 2-way alias (free)
constexpr int SXH_  = 72;     // bf16 stride: 144B -> 2-way alias (free), 16B aligned

__global__ __launch_bounds__(256, 4) void gemm_kernel(
    const float* __restrict__ obs, const float* __restrict__ hidden,
    const float* __restrict__ b_fc1,
    const float* __restrict__ b_ih, const float* __restrict__ b_hh,
    const float* __restrict__ w_fc2, const float* __restrict__ b_fc2,
    const void* __restrict__ wsv,
    float* q5,                       // ALIASED: obs_out (read) then q (write)
    float* __restrict__ h_out) {

  __shared__ __align__(16) __bf16 A_obs[ROWS_ * SOB_];
  __shared__ __align__(16) __bf16 A_x[ROWS_ * SXH_];

  const int tid  = threadIdx.x;
  const int wv   = tid >> 6;
  const int lane = tid & 63;
  const int l    = lane & 15;
  const int quad = lane >> 4;
  const int r0   = wv * 16;
  const long gr0 = (long)blockIdx.x * ROWS_;

  const __bf16* Wih = (const __bf16*)((const char*)wsv + 512);
  const __bf16* Whh = Wih + 192 * 64;
  const __bf16* Wf1 = Whh + 192 * 64;

  // ---- phase 0: ISSUE all global loads (no dependent use yet) ----
  const float* src = obs + (gr0 + r0) * OBS_DIM_;
  f32x4 vobs[6];
  #pragma unroll
  for (int k = 0; k < 6; ++k) {
    int idx = lane + 64 * k;
    if (idx < 340) vobs[k] = *(const f32x4*)&src[idx * 4];
  }
  const float* o5 = q5 + (gr0 + r0) * NL_;
  float vo5a = o5[lane];
  float vo5b = (lane < 16) ? o5[lane + 64] : 0.0f;

  const float* hrow_g = hidden + (gr0 + r0 + l) * HID_;
  f32x4 vha0 = *(const f32x4*)&hrow_g[quad * 8];
  f32x4 vha1 = *(const f32x4*)&hrow_g[quad * 8 + 4];
  f32x4 vhb0 = *(const f32x4*)&hrow_g[32 + quad * 8];
  f32x4 vhb1 = *(const f32x4*)&hrow_g[32 + quad * 8 + 4];

  bf16x8 bf1[3][4];                // fc1 B-fragments, L2-resident, hoisted
  #pragma unroll
  for (int ks = 0; ks < 3; ++ks)
    #pragma unroll
    for (int nt = 0; nt < 4; ++nt)
      bf1[ks][nt] = *(const bf16x8*)&Wf1[(nt * 16 + l) * 96 + ks * 32 + quad * 8];

  // ---- phase 1: convert + LDS staging (wave-local, no barrier) ----
  #pragma unroll
  for (int k = 0; k < 6; ++k) {
    int idx = lane + 64 * k;
    if (idx < 340) {
      #pragma unroll
      for (int e = 0; e < 4; ++e) {
        int fe = idx * 4 + e;
        int rr = fe / 85, cc = fe - 85 * rr;
        A_obs[(r0 + rr) * SOB_ + cc] = (__bf16)vobs[k][e];
      }
    }
  }
  {
    int rr = lane / NL_, cc = lane - NL_ * rr;
    A_obs[(r0 + rr) * SOB_ + 85 + cc] = (__bf16)vo5a;
  }
  if (lane < 16) {
    int it = lane + 64;
    int rr = it / NL_, cc = it - NL_ * rr;
    A_obs[(r0 + rr) * SOB_ + 85 + cc] = (__bf16)vo5b;
  }
  #pragma unroll
  for (int p = 0; p < 2; ++p) {                 // zero K-pad cols 90..95
    int it = lane + 64 * p;
    if (it < 96) {
      int rr = it / 6, cc = it - 6 * rr;
      A_obs[(r0 + rr) * SOB_ + 90 + cc] = (__bf16)0.0f;
    }
  }

  bf16x8 ah[2];
  {
    bf16x8 t;
    t[0] = (__bf16)vha0[0]; t[1] = (__bf16)vha0[1]; t[2] = (__bf16)vha0[2]; t[3] = (__bf16)vha0[3];
    t[4] = (__bf16)vha1[0]; t[5] = (__bf16)vha1[1]; t[6] = (__bf16)vha1[2]; t[7] = (__bf16)vha1[3];
    ah[0] = t;
    t[0] = (__bf16)vhb0[0]; t[1] = (__bf16)vhb0[1]; t[2] = (__bf16)vhb0[2]; t[3] = (__bf16)vhb0[3];
    t[4] = (__bf16)vhb1[0]; t[5] = (__bf16)vhb1[1]; t[6] = (__bf16)vhb1[2]; t[7] = (__bf16)vhb1[3];
    ah[1] = t;
  }

  const f32x4 zero4 = {0.0f, 0.0f, 0.0f, 0.0f};

  // fc1: C[16x64] = A_obs[16x96] @ Wf1T
  f32x4 cx[4];
  #pragma unroll
  for (int nt = 0; nt < 4; ++nt) cx[nt] = zero4;
  #pragma unroll
  for (int ks = 0; ks < 3; ++ks) {
    bf16x8 af = *(const bf16x8*)&A_obs[(r0 + l) * SOB_ + ks * 32 + quad * 8];
    #pragma unroll
    for (int nt = 0; nt < 4; ++nt)
      cx[nt] = __builtin_amdgcn_mfma_f32_16x16x32_bf16(af, bf1[ks][nt], cx[nt], 0, 0, 0);
  }
  #pragma unroll
  for (int nt = 0; nt < 4; ++nt) {
    float bias = b_fc1[nt * 16 + l];
    #pragma unroll
    for (int rg = 0; rg < 4; ++rg) {
      float xv = fmaxf(cx[nt][rg] + bias, 0.0f);
      A_x[(r0 + quad * 4 + rg) * SXH_ + nt * 16 + l] = (__bf16)xv;
    }
  }

  // GRU GEMMs (B-columns permuted: tile nt, lane l == orig col 4l+nt)
  bf16x8 ax[2];
  #pragma unroll
  for (int ks = 0; ks < 2; ++ks)
    ax[ks] = *(const bf16x8*)&A_x[(r0 + l) * SXH_ + ks * 32 + quad * 8];

  f32x4 crz[8], cni[4], cnh[4];
  #pragma unroll
  for (int nt = 0; nt < 8; ++nt) crz[nt] = zero4;
  #pragma unroll
  for (int nt = 0; nt < 4; ++nt) { cni[nt] = zero4; cnh[nt] = zero4; }
  #pragma unroll
  for (int nt = 0; nt < 8; ++nt) {
    #pragma unroll
    for (int ks = 0; ks < 2; ++ks) {
      bf16x8 bi = *(const bf16x8*)&Wih[(nt * 16 + l) * 64 + ks * 32 + quad * 8];
      crz[nt] = __builtin_amdgcn_mfma_f32_16x16x32_bf16(ax[ks], bi, crz[nt], 0, 0, 0);
      bf16x8 bh = *(const bf16x8*)&Whh[(nt * 16 + l) * 64 + ks * 32 + quad * 8];
      crz[nt] = __builtin_amdgcn_mfma_f32_16x16x32_bf16(ah[ks], bh, crz[nt], 0, 0, 0);
    }
  }
  #pragma unroll
  for (int nt = 0; nt < 4; ++nt) {
    #pragma unroll
    for (int ks = 0; ks < 2; ++ks) {
      bf16x8 bi = *(const bf16x8*)&Wih[(128 + nt * 16 + l) * 64 + ks * 32 + quad * 8];
      cni[nt] = __builtin_amdgcn_mfma_f32_16x16x32_bf16(ax[ks], bi, cni[nt], 0, 0, 0);
      bf16x8 bh = *(const bf16x8*)&Whh[(128 + nt * 16 + l) * 64 + ks * 32 + quad * 8];
      cnh[nt] = __builtin_amdgcn_mfma_f32_16x16x32_bf16(ah[ks], bh, cnh[nt], 0, 0, 0);
    }
  }

  // epilogue: lane l owns orig cols 4l..4l+3 (t indexes within the quad).
  // C layout: row = quad*4+rg, value for orig col 4l+t is crz[t]/crz[4+t]/...
  const long grow = gr0 + r0 + quad * 4;

  f32x4 br4, bz4, bin4, bhn4;
  {
    f32x4 a0 = *(const f32x4*)&b_ih[4 * l];
    f32x4 a1 = *(const f32x4*)&b_hh[4 * l];
    br4 = a0 + a1;
    a0 = *(const f32x4*)&b_ih[64 + 4 * l];
    a1 = *(const f32x4*)&b_hh[64 + 4 * l];
    bz4 = a0 + a1;
    bin4 = *(const f32x4*)&b_ih[128 + 4 * l];
    bhn4 = *(const f32x4*)&b_hh[128 + 4 * l];
  }
  f32x4 w20[5];                    // w_fc2 rows 4l..4l+3 = 20 contiguous floats
  #pragma unroll
  for (int j = 0; j < 5; ++j) w20[j] = *(const f32x4*)&w_fc2[20 * l + 4 * j];

  float qp[4][NACT_];
  #pragma unroll
  for (int rg = 0; rg < 4; ++rg)
    #pragma unroll
    for (int c = 0; c < NACT_; ++c) qp[rg][c] = 0.0f;

  #pragma unroll
  for (int rg = 0; rg < 4; ++rg) {
    f32x4 hold = *(const f32x4*)&hidden[(grow + rg) * HID_ + 4 * l];
    f32x4 hnew;
    #pragma unroll
    for (int t = 0; t < 4; ++t) {
      float rr = sigmoidf(crz[t][rg] + br4[t]);
      float zz = sigmoidf(crz[4 + t][rg] + bz4[t]);
      float nn = tanh_fast(cni[t][rg] + bin4[t] + rr * (cnh[t][rg] + bhn4[t]));
      float hn = (1.0f - zz) * nn + zz * hold[t];
      hnew[t] = hn;
      #pragma unroll
      for (int c = 0; c < NACT_; ++c)
        qp[rg][c] += hn * w20[(5 * t + c) >> 2][(5 * t + c) & 3];
    }
    *(f32x4*)&h_out[(grow + rg) * HID_ + 4 * l] = hnew;
  }

  #pragma unroll
  for (int m = 1; m < 16; m <<= 1) {
    #pragma unroll
    for (int rg = 0; rg < 4; ++rg)
      #pragma unroll
      for (int c = 0; c < NACT_; ++c) qp[rg][c] += __shfl_xor(qp[rg][c], m, 64);
  }
  if (l < NACT_) {
    #pragma unroll
    for (int rg = 0; rg < 4; ++rg) {
      float qv = qp[rg][0];
      if (l == 1) qv = qp[rg][1];
      if (l == 2) qv = qp[rg][2];
      if (l == 3) qv = qp[rg][3];
      if (l == 4) qv = qp[rg][4];
      q5[(grow + rg) * NACT_ + l] = qv + b_fc2[l];
    }
  }
}

}  // namespace

extern "C" void kernel_launch(void* const* d_in, const int* in_sizes, int n_in,
                              void* d_out, int out_size, void* d_ws, size_t ws_size,
                              hipStream_t stream) {
  const float* obs    = (const float*)d_in[0];
  const float* hidden = (const float*)d_in[1];
  const float* w_in0  = (const float*)d_in[2];
  const float* b_in0  = (const float*)d_in[3];
  const float* w_in1  = (const float*)d_in[4];
  const float* b_in1  = (const float*)d_in[5];
  const float* w_in2  = (const float*)d_in[6];
  const float* b_in2  = (const float*)d_in[7];
  const float* W      = (const float*)d_in[8];
  const float* a      = (const float*)d_in[9];
  const float* w_o1   = (const float*)d_in[10];
  const float* b_o1   = (const float*)d_in[11];
  const float* w_o2   = (const float*)d_in[12];
  const float* b_o2   = (const float*)d_in[13];
  const float* w_o3   = (const float*)d_in[14];
  const float* b_o3   = (const float*)d_in[15];
  const float* w_fc1  = (const float*)d_in[16];
  const float* b_fc1  = (const float*)d_in[17];
  const float* w_ih   = (const float*)d_in[18];
  const float* w_hh   = (const float*)d_in[19];
  const float* b_ih   = (const float*)d_in[20];
  const float* b_hh   = (const float*)d_in[21];
  const float* w_fc2  = (const float*)d_in[22];
  const float* b_fc2  = (const float*)d_in[23];

  float* q_out = (float*)d_out;                  // (B,5) -- also obs_out scratch
  float* h_out = q_out + (long)B_ * NACT_;       // (B,64)
  const float* Wa = (const float*)d_ws;

  prep_kernel<<<48, 256, 0, stream>>>(W, a, w_ih, w_hh, w_fc1, d_ws);
  front_kernel<<<B_ / 16, 256, 0, stream>>>(
      obs, w_in0, b_in0, w_in1, b_in1, w_in2, b_in2,
      w_o1, b_o1, w_o2, b_o2, w_o3, b_o3, Wa, q_out);
  gemm_kernel<<<B_ / ROWS_, 256, 0, stream>>>(
      obs, hidden, b_fc1, b_ih, b_hh, w_fc2, b_fc2, d_ws, q_out, h_out);
}